// Round 4
// baseline (139.073 us; speedup 1.0000x reference)
//
#include <hip/hip_runtime.h>
#include <stdint.h>

typedef __bf16 bf16x8 __attribute__((ext_vector_type(8)));
typedef float  f32x4  __attribute__((ext_vector_type(4)));
typedef uint32_t u32x4 __attribute__((ext_vector_type(4)));

__device__ __forceinline__ uint16_t f2bf(float f) {
    uint32_t u = __builtin_bit_cast(uint32_t, f);
    u += 0x7FFFu + ((u >> 16) & 1u);          // round-to-nearest-even
    return (uint16_t)(u >> 16);
}

// ---------------------------------------------------------------------------
// Kernel 1: Q [b][c 256][i 32][j 32] f32 -> Qt [b][ih 2][j 32][ch 32][il 16][8] bf16
//   where c = ch*8 + t, i = ih*16 + il.  Corr's B-fragment load = 1 KB contiguous.
// Also zeroes d_out (saves a separate memset dispatch; corr atomically adds).
// ---------------------------------------------------------------------------
__global__ __launch_bounds__(256) void qtrans_kernel(const float* __restrict__ Q,
                                                     uint16_t* __restrict__ Qt,
                                                     float* __restrict__ out) {
    // T[c8 8][i 32][j 33] f32, c8-stride 1064 so bank = 8*c8 + i + j
    __shared__ float T[8 * 1064];
    const int ch = blockIdx.x, b = blockIdx.y;
    const int tid = threadIdx.x;

    {   // zero out[16*65*65] across the whole grid (512 blocks x 256 thr)
        int g = (b * 32 + ch) * 256 + tid;             // 0..131071
        if (g < 67600) out[g] = 0.f;
    }

    const float* src = Q + ((size_t)(b * 256 + ch * 8)) * 1024;
    #pragma unroll
    for (int it = 0; it < 32; ++it) {                  // 8192 f32, coalesced
        int r = tid + it * 256;
        int c8 = r >> 10, rem = r & 1023;
        T[c8 * 1064 + (rem >> 5) * 33 + (rem & 31)] = src[(size_t)c8 * 1024 + rem];
    }
    __syncthreads();

    uint32_t* dst = (uint32_t*)Qt;                     // write bf16 pairs
    #pragma unroll
    for (int it = 0; it < 16; ++it) {                  // 4096 pairs
        int o2 = tid + it * 256;
        int t  = (o2 & 3) * 2;
        int il = (o2 >> 2) & 15;
        int j  = (o2 >> 6) & 31;
        int ih = (o2 >> 11) & 1;
        float v0 = T[t * 1064 + (ih * 16 + il) * 33 + j];
        float v1 = T[(t + 1) * 1064 + (ih * 16 + il) * 33 + j];
        uint32_t pk = (uint32_t)f2bf(v0) | ((uint32_t)f2bf(v1) << 16);
        size_t oi = ((((size_t)(b * 2 + ih) * 32 + j) * 32 + ch) * 16 + il) * 4 + (t >> 1);
        dst[oi] = pk;
    }
}

// ---------------------------------------------------------------------------
// Kernel 2: block=(b,d).  P[x][i] = sum_{j,c} S[b,c,d,x+j-16]*Q[b,c,i,j],
// then epilogue atomically adds P into out[b, y=d-i+16, x].
//   LDS S_l[ch 32][row 80] of 16B chunks; row = S-row + 16 (rows 0..15 = zeros,
//   OOB clamped to zero-row 0) -> zero-conflict b128 reads, no edge masking.
//   Wave w owns j0a = w+4jj (0..15) and j0b = j0a+16; shared A fragments:
//   base'(t) = j0a + 16t serves (m=t, j0a) and (m=t-1, j0b): 5 reads / 18 MFMA.
//   Grid: flat 1024; XCD-aware decode (assumes XCD = blockIdx % 8 round-robin)
//   so each XCD touches only 2 b values -> Qt working set 1 MB, L2-resident.
// ---------------------------------------------------------------------------
__global__ __launch_bounds__(256, 4) void corr_kernel(const float* __restrict__ S,
                                                      const uint16_t* __restrict__ Qt,
                                                      float* __restrict__ out) {
    __shared__ __align__(16) char smem[40960];         // 40 KB -> 4 blocks/CU
    uint16_t* S_l = (uint16_t*)smem;                   // [ch][row]: idx = ch*640 + row*8
    float*    Pw  = (float*)smem;                      // overlay: [4][iv 32][x 80]

    const int flat = blockIdx.x;                       // 0..1023
    const int b = ((flat & 7) << 1) | ((flat >> 9) & 1);  // 2 b's per XCD
    const int d = (flat >> 3) & 63;
    const int tid = threadIdx.x, wave = tid >> 6, lane = tid & 63;
    const int l15 = lane & 15, l4 = lane >> 4;

    // ---- zero-fill pad rows 0..15 for all ch (8 KB)
    {
        const u32x4 z = {};
        for (int zi = tid; zi < 512; zi += 256) {
            int ch = zi >> 4, r = zi & 15;
            *(u32x4*)&S_l[ch * 640 + r * 8] = z;
        }
    }
    // ---- stage S[b,:,d,:] -> S_l[ch][sx+16] (bf16). Writes lane-contiguous.
    {
        const int sx = tid & 63, w = tid >> 6;
        const float* sp = S + ((size_t)b * 256) * 4096 + (size_t)d * 64;
        #pragma unroll
        for (int k = 0; k < 8; ++k) {
            int ch = w * 8 + k;
            float v[8];
            #pragma unroll
            for (int cc = 0; cc < 8; ++cc)
                v[cc] = sp[(size_t)(ch * 8 + cc) * 4096 + sx];   // 256B coalesced
            u32x4 pk;
            #pragma unroll
            for (int q = 0; q < 4; ++q)
                pk[q] = (uint32_t)f2bf(v[2 * q]) | ((uint32_t)f2bf(v[2 * q + 1]) << 16);
            *(u32x4*)&S_l[ch * 640 + (sx + 16) * 8] = pk;        // contiguous 1KB/wave
        }
    }
    __syncthreads();

    f32x4 acc[5][2] = {};

    #pragma unroll
    for (int jj = 0; jj < 4; ++jj) {
        const int j0a = wave + jj * 4;                 // 0..15 ; j0b = j0a+16
        const uint16_t* qa0 = Qt + (((size_t)b * 2 + 0) * 32 + j0a) * 4096 + l4 * 128 + l15 * 8;
        const uint16_t* qa1 = Qt + (((size_t)b * 2 + 1) * 32 + j0a) * 4096 + l4 * 128 + l15 * 8;
        const uint16_t* qb0 = qa0 + 16 * 4096;
        const uint16_t* qb1 = qa1 + 16 * 4096;

        int rowt[5];
        #pragma unroll
        for (int t = 0; t < 5; ++t) {
            int rr = j0a + t * 16 + l15;               // <= 94
            rowt[t] = (rr < 80) ? rr : 0;              // OOB -> zero-row (garbage x>=65)
        }

        #pragma unroll
        for (int s = 0; s < 8; ++s) {
            bf16x8 Ba0 = *(const bf16x8*)(qa0 + s * 512);
            bf16x8 Ba1 = *(const bf16x8*)(qa1 + s * 512);
            bf16x8 Bb0 = *(const bf16x8*)(qb0 + s * 512);
            bf16x8 Bb1 = *(const bf16x8*)(qb1 + s * 512);
            const int chb = (s * 4 + l4) * 640;
            bf16x8 A[5];
            #pragma unroll
            for (int t = 0; t < 5; ++t)
                A[t] = *(const bf16x8*)&S_l[chb + rowt[t] * 8];  // conflict-free b128
            #pragma unroll
            for (int t = 0; t < 5; ++t) {
                acc[t][0] = __builtin_amdgcn_mfma_f32_16x16x32_bf16(A[t], Ba0, acc[t][0], 0, 0, 0);
                acc[t][1] = __builtin_amdgcn_mfma_f32_16x16x32_bf16(A[t], Ba1, acc[t][1], 0, 0, 0);
            }
            #pragma unroll
            for (int t = 1; t < 5; ++t) {
                acc[t - 1][0] = __builtin_amdgcn_mfma_f32_16x16x32_bf16(A[t], Bb0, acc[t - 1][0], 0, 0, 0);
                acc[t - 1][1] = __builtin_amdgcn_mfma_f32_16x16x32_bf16(A[t], Bb1, acc[t - 1][1], 0, 0, 0);
            }
        }
    }

    // ---- merge 4 wave-partials in LDS, then atomic-add into out
    __syncthreads();
    {
        float* pw = Pw + wave * 2560;                  // [iv 32][x 80]
        #pragma unroll
        for (int m = 0; m < 5; ++m)
            #pragma unroll
            for (int n = 0; n < 2; ++n)
                *(f32x4*)&pw[(n * 16 + l15) * 80 + m * 16 + l4 * 4] = acc[m][n];
    }
    __syncthreads();
    for (int e = tid; e < 65 * 32; e += 256) {
        int x = e % 65, i = e / 65;
        int y = d - i + 16;
        if ((unsigned)y < 65u) {
            float v = Pw[0 * 2560 + i * 80 + x] + Pw[1 * 2560 + i * 80 + x]
                    + Pw[2 * 2560 + i * 80 + x] + Pw[3 * 2560 + i * 80 + x];
            atomicAdd(out + ((size_t)b * 4225 + (size_t)y * 65 + x), v);
        }
    }
}

// ---------------------------------------------------------------------------
// fp32 fallback (only if workspace is too small) — slow but exact
// ---------------------------------------------------------------------------
__global__ __launch_bounds__(256) void naive_kernel(const float* __restrict__ Q,
                                                    const float* __restrict__ S,
                                                    float* __restrict__ out) {
    int gid = blockIdx.x * 256 + threadIdx.x;
    if (gid >= 67600) return;
    int b = gid / 4225, r = gid % 4225, y = r / 65, x = r % 65;
    int jlo = 16 - x; if (jlo < 0) jlo = 0;
    int jhi = 80 - x; if (jhi > 32) jhi = 32;
    float acc = 0.f;
    for (int c = 0; c < 256; ++c) {
        const float* Sb = S + ((size_t)(b * 256 + c)) * 4096;
        const float* Qb = Q + ((size_t)(b * 256 + c)) * 1024;
        for (int i = 0; i < 32; ++i) {
            int dd = y + i - 16;
            if ((unsigned)dd >= 64u) continue;
            const float* Sr = Sb + dd * 64 + (x - 16);
            const float* Qr = Qb + i * 32;
            for (int j = jlo; j < jhi; ++j) acc += Sr[j] * Qr[j];
        }
    }
    out[gid] = acc;
}

extern "C" void kernel_launch(void* const* d_in, const int* in_sizes, int n_in,
                              void* d_out, int out_size, void* d_ws, size_t ws_size,
                              hipStream_t stream) {
    (void)in_sizes; (void)n_in; (void)out_size;
    const float* Q = (const float*)d_in[0];   // [16,256,32,32] f32
    const float* S = (const float*)d_in[1];   // [16,256,64,64] f32
    float* out = (float*)d_out;               // [16,1,65,65] f32

    const size_t QT_BYTES = (size_t)16 * 2 * 32 * 32 * 16 * 8 * 2;  // 8,388,608

    if (ws_size < QT_BYTES) {
        naive_kernel<<<(67600 + 255) / 256, 256, 0, stream>>>(Q, S, out);
        return;
    }
    uint16_t* Qt = (uint16_t*)d_ws;

    qtrans_kernel<<<dim3(32, 16), 256, 0, stream>>>(Q, Qt, out);
    corr_kernel<<<dim3(1024), 256, 0, stream>>>(S, Qt, out);
}